// Round 5
// baseline (1228.629 us; speedup 1.0000x reference)
//
#include <hip/hip_runtime.h>
#include <cstdint>
#include <cstddef>

// ---------------------------------------------------------------------------
// GCN 3-layer + FC head. Round 5: bucketed CSR fill (kills the 108MB
// write-allocate scatter), memset deg, merged prep, spmv unroll-4.
// ---------------------------------------------------------------------------

typedef __attribute__((ext_vector_type(4))) float f32x4;
typedef __attribute__((ext_vector_type(8))) short bf16x8;
typedef unsigned short u16;

__device__ __forceinline__ float bf2f(unsigned int u) {
  union { unsigned int i; float f; } v;
  v.i = u << 16;
  return v.f;
}
__device__ __forceinline__ u16 f2bf(float f) {
  union { float f; unsigned int i; } v;
  v.f = f;
  unsigned int i = v.i;
  return (u16)((i + 0x7FFFu + ((i >> 16) & 1u)) >> 16);  // RNE
}

// ---------------- graph preprocessing ----------------
// deg[] starts at 0 (hipMemsetAsync); counts real in-edges only. The +1
// self-loop is folded into the scans and k_write.

__global__ __launch_bounds__(256) void k_count(const int* __restrict__ ei,
                                               int* __restrict__ deg, int E) {
  int e = blockIdx.x * 256 + threadIdx.x;
  if (e < E) atomicAdd(&deg[ei[E + e]], 1);   // dst half
}

// per-256-node-block sums of (deg[i]+1)
__global__ __launch_bounds__(256) void k_partial(const int* __restrict__ deg,
                                                 int* __restrict__ partial, int n) {
  __shared__ int sm[256];
  int t = threadIdx.x;
  int i = blockIdx.x * 256 + t;
  sm[t] = (i < n) ? deg[i] + 1 : 0;
  __syncthreads();
#pragma unroll
  for (int off = 128; off > 0; off >>= 1) {
    if (t < off) sm[t] += sm[t + off];
    __syncthreads();
  }
  if (t == 0) partial[blockIdx.x] = sm[0];
}

// one block: scan partial -> poff (rowptr block offsets);
// scan (partial - nodes_in_block) -> boff/bfill (edge-bucket scratch offsets).
__global__ __launch_bounds__(512) void k_scanp(const int* __restrict__ partial,
                                               int* __restrict__ poff,
                                               int* __restrict__ boff,
                                               int* __restrict__ bfill,
                                               int nb, int* __restrict__ rowptr,
                                               int n, int total, int E) {
  __shared__ int sm[512];
  int t = threadIdx.x;
  int p = (t < nb) ? partial[t] : 0;
  // scan 1: block offsets for rowptr
  sm[t] = p;
  __syncthreads();
  for (int off = 1; off < 512; off <<= 1) {
    int v = (t >= off) ? sm[t - off] : 0;
    __syncthreads();
    sm[t] += v;
    __syncthreads();
  }
  if (t < nb) poff[t] = (t == 0) ? 0 : sm[t - 1];
  __syncthreads();
  // scan 2: per-bucket edge counts = partial - nodes_in_block
  int nodes = 0;
  if (t < nb) nodes = min(256, n - t * 256);
  sm[t] = p - nodes;
  __syncthreads();
  for (int off = 1; off < 512; off <<= 1) {
    int v = (t >= off) ? sm[t - off] : 0;
    __syncthreads();
    sm[t] += v;
    __syncthreads();
  }
  if (t < nb) {
    int ex = (t == 0) ? 0 : sm[t - 1];
    boff[t] = ex;
    bfill[t] = ex;
  }
  if (t == 0) {
    rowptr[n] = total;
    boff[nb] = E;
  }
}

// per-block rescan of (deg+1) + write rowptr, self-loop slot, fillctr, dis
__global__ __launch_bounds__(256) void k_write(const int* __restrict__ deg,
                                               const int* __restrict__ poff,
                                               int* __restrict__ rowptr,
                                               int* __restrict__ fillctr,
                                               int* __restrict__ col,
                                               float* __restrict__ dis, int n) {
  __shared__ int sm[256];
  int t = threadIdx.x;
  int i = blockIdx.x * 256 + t;
  int v = (i < n) ? deg[i] + 1 : 0;
  sm[t] = v;
  __syncthreads();
  for (int off = 1; off < 256; off <<= 1) {
    int u = (t >= off) ? sm[t - off] : 0;
    __syncthreads();
    sm[t] += u;
    __syncthreads();
  }
  if (i < n) {
    int excl = poff[blockIdx.x] + sm[t] - v;
    rowptr[i] = excl;
    col[excl] = i;          // self-loop gets the fixed first slot
    fillctr[i] = excl + 1;  // atomic fill starts after it
    dis[i] = rsqrtf((float)v);
  }
}

// pass B: bin edges into bucket-major scratch, packed (src<<8 | dst&255).
// Writes cluster at each bucket's tail line -> L2 write-merge.
__global__ __launch_bounds__(256) void k_bin(const int* __restrict__ ei,
                                             int* __restrict__ bfill,
                                             unsigned int* __restrict__ ebuf,
                                             int E) {
  int e = blockIdx.x * 256 + threadIdx.x;
  if (e >= E) return;
  int s = ei[e];
  int d = ei[E + e];
  int pos = atomicAdd(&bfill[d >> 8], 1);
  ebuf[pos] = ((unsigned int)s << 8) | (unsigned int)(d & 255);
}

// pass C: per-bucket CSR fill; scatter confined to the bucket's ~17KB window.
__global__ __launch_bounds__(256) void k_cfill(const unsigned int* __restrict__ ebuf,
                                               const int* __restrict__ boff,
                                               int* __restrict__ fillctr,
                                               int* __restrict__ col) {
  int b = blockIdx.x;
  int beg = boff[b];
  int end = boff[b + 1];
  for (int t = beg + threadIdx.x; t < end; t += 256) {
    unsigned int pk = ebuf[t];
    int s = (int)(pk >> 8);
    int d = (b << 8) | (int)(pk & 255u);
    int pos = atomicAdd(&fillctr[d], 1);
    col[pos] = s;
  }
}

// ---------------- dtype prep ----------------

// X fp32 -> bf16, 8 elems/thread
__global__ __launch_bounds__(256) void k_cvt(const float* __restrict__ src,
                                             u16* __restrict__ dst, int total8) {
  int i = blockIdx.x * 256 + threadIdx.x;
  if (i >= total8) return;
  size_t b = (size_t)i * 8;
  float4 a0 = *(const float4*)(src + b);
  float4 a1 = *(const float4*)(src + b + 4);
  u16 o[8] = {f2bf(a0.x), f2bf(a0.y), f2bf(a0.z), f2bf(a0.w),
              f2bf(a1.x), f2bf(a1.y), f2bf(a1.z), f2bf(a1.w)};
  *(ulonglong2*)(dst + b) = *(ulonglong2*)o;
}

// blocks 0..767: WT[z][nr][k] = bf16(W_z[k][nr]); blocks 768..770: bias sums
__global__ __launch_bounds__(128) void k_prep(const float* __restrict__ w0,
                                              const float* __restrict__ w1,
                                              const float* __restrict__ w2,
                                              const float* __restrict__ w3,
                                              const float* __restrict__ w4,
                                              const float* __restrict__ w5,
                                              const float* __restrict__ g1,
                                              const float* __restrict__ l1,
                                              const float* __restrict__ g2,
                                              const float* __restrict__ l2,
                                              const float* __restrict__ g3,
                                              const float* __restrict__ l3,
                                              u16* __restrict__ wt,
                                              float* __restrict__ bias) {
  int bx = blockIdx.x;
  if (bx < 768) {
    int z = bx >> 7, nr = bx & 127, k = threadIdx.x;
    const float* Ws[6] = {w0, w1, w2, w3, w4, w5};
    wt[(size_t)z * 16384 + nr * 128 + k] = f2bf(Ws[z][k * 128 + nr]);
  } else {
    int t = (bx - 768) * 128 + threadIdx.x;
    if (t < 384) {
      const float* gs[3] = {g1, g2, g3};
      const float* ls[3] = {l1, l2, l3};
      bias[t] = gs[t >> 7][t & 127] + ls[t >> 7][t & 127];
    }
  }
}

// ---------------------------------------------------------------------------
// SXb[i] = bf16( dis[i] * sum_j dis[col[j]] * Xb[col[j], :] )
// one wave/node, uint (2xbf16)/lane, fp32 accum, 4-edge unroll for MLP.
// ---------------------------------------------------------------------------
__global__ __launch_bounds__(256) void k_spmv_bf(const int* __restrict__ rowptr,
                                                 const int* __restrict__ col,
                                                 const float* __restrict__ dis,
                                                 const u16* __restrict__ Xb,
                                                 u16* __restrict__ SXb, int n) {
  const int wave = threadIdx.x >> 6;
  const int lane = threadIdx.x & 63;
  const int i = blockIdx.x * 4 + wave;
  if (i >= n) return;
  int j = rowptr[i];
  const int end = rowptr[i + 1];
  float ax = 0.f, ay = 0.f;
  for (; j + 3 < end; j += 4) {
    int c0 = col[j], c1 = col[j + 1], c2 = col[j + 2], c3 = col[j + 3];
    float w0 = dis[c0], w1 = dis[c1], w2 = dis[c2], w3 = dis[c3];
    unsigned int q0 = *(const unsigned int*)(Xb + (size_t)c0 * 128 + lane * 2);
    unsigned int q1 = *(const unsigned int*)(Xb + (size_t)c1 * 128 + lane * 2);
    unsigned int q2 = *(const unsigned int*)(Xb + (size_t)c2 * 128 + lane * 2);
    unsigned int q3 = *(const unsigned int*)(Xb + (size_t)c3 * 128 + lane * 2);
    ax = fmaf(bf2f(q0 & 0xffffu), w0, ax);
    ay = fmaf(bf2f(q0 >> 16), w0, ay);
    ax = fmaf(bf2f(q1 & 0xffffu), w1, ax);
    ay = fmaf(bf2f(q1 >> 16), w1, ay);
    ax = fmaf(bf2f(q2 & 0xffffu), w2, ax);
    ay = fmaf(bf2f(q2 >> 16), w2, ay);
    ax = fmaf(bf2f(q3 & 0xffffu), w3, ax);
    ay = fmaf(bf2f(q3 >> 16), w3, ay);
  }
  for (; j < end; ++j) {
    int c0 = col[j];
    float w0 = dis[c0];
    unsigned int q0 = *(const unsigned int*)(Xb + (size_t)c0 * 128 + lane * 2);
    ax = fmaf(bf2f(q0 & 0xffffu), w0, ax);
    ay = fmaf(bf2f(q0 >> 16), w0, ay);
  }
  float di = dis[i];
  ax *= di;
  ay *= di;
  unsigned int o = (unsigned int)f2bf(ax) | ((unsigned int)f2bf(ay) << 16);
  *(unsigned int*)(SXb + (size_t)i * 128 + lane * 2) = o;
}

// ---------------------------------------------------------------------------
// MFMA fused layer:  out = lrelu( A0@W0 + A1@W1 + bias )
// A0,A1 bf16 row-major [M,128]; W0T,W1T bf16 [n][k]. No LDS.
// 4 waves/block, wave owns 32 rows; acc 2x8 f32x4.
// gfx950 16x16x32 mapping: A/B lane l -> row/col l&15, k (l>>4)*8+e;
//                          D lane l -> col l&15, row (l>>4)*4+e.
// ---------------------------------------------------------------------------
__global__ __launch_bounds__(256) void k_mfma(const u16* __restrict__ A0,
                                              const u16* __restrict__ A1,
                                              const u16* __restrict__ W0T,
                                              const u16* __restrict__ W1T,
                                              const float* __restrict__ bias,
                                              u16* __restrict__ outb,
                                              float* __restrict__ outf, int M) {
  const int lane = threadIdx.x & 63;
  const int wv = threadIdx.x >> 6;
  const int row0 = blockIdx.x * 128 + wv * 32;
  const int r = lane & 15;
  const int kg = lane >> 4;

  f32x4 acc[2][8];
#pragma unroll
  for (int a = 0; a < 2; ++a)
#pragma unroll
    for (int j = 0; j < 8; ++j) acc[a][j] = (f32x4){0.f, 0.f, 0.f, 0.f};

  const int ra0 = min(row0 + r, M - 1);
  const int ra1 = min(row0 + 16 + r, M - 1);

#pragma unroll
  for (int p = 0; p < 2; ++p) {
    const u16* A = p ? A1 : A0;
    const u16* WT = p ? W1T : W0T;
#pragma unroll
    for (int kk = 0; kk < 4; ++kk) {
      const int k0 = kk * 32 + kg * 8;
      bf16x8 a0 = *(const bf16x8*)(A + (size_t)ra0 * 128 + k0);
      bf16x8 a1 = *(const bf16x8*)(A + (size_t)ra1 * 128 + k0);
#pragma unroll
      for (int j = 0; j < 8; ++j) {
        bf16x8 b = *(const bf16x8*)(WT + (size_t)(j * 16 + r) * 128 + k0);
        acc[0][j] = __builtin_amdgcn_mfma_f32_16x16x32_bf16(a0, b, acc[0][j], 0, 0, 0);
        acc[1][j] = __builtin_amdgcn_mfma_f32_16x16x32_bf16(a1, b, acc[1][j], 0, 0, 0);
      }
    }
  }

#pragma unroll
  for (int rf = 0; rf < 2; ++rf)
#pragma unroll
    for (int e = 0; e < 4; ++e) {
      const int row = row0 + rf * 16 + kg * 4 + e;
      if (row >= M) continue;
#pragma unroll
      for (int j = 0; j < 8; ++j) {
        const int c = j * 16 + r;
        float v = acc[rf][j][e] + bias[c];
        v = (v > 0.f) ? v : 0.01f * v;
        if (outf) outf[(size_t)row * 128 + c] = v;
        else outb[(size_t)row * 128 + c] = f2bf(v);
      }
    }
}

// ---------------------------------------------------------------------------
// FC head: y = h @ fcw + fcb   ([N,128]x[128,64] fp32); one wave per row.
// ---------------------------------------------------------------------------
__global__ __launch_bounds__(256) void k_fc(const float* __restrict__ h,
                                            const float* __restrict__ fcw,
                                            const float* __restrict__ fcb,
                                            float* __restrict__ y, int n) {
  __shared__ float ws[128 * 64];
  for (int t = threadIdx.x; t < 128 * 64; t += 256) ws[t] = fcw[t];
  __syncthreads();
  const int wave = threadIdx.x >> 6;
  const int lane = threadIdx.x & 63;
  const int i = blockIdx.x * 4 + wave;
  if (i >= n) return;
  const float* hr = h + (size_t)i * 128;
  float acc = fcb[lane];
#pragma unroll 8
  for (int k4 = 0; k4 < 32; ++k4) {
    float4 hv = *(const float4*)(hr + k4 * 4);
    acc = fmaf(hv.x, ws[(k4 * 4 + 0) * 64 + lane], acc);
    acc = fmaf(hv.y, ws[(k4 * 4 + 1) * 64 + lane], acc);
    acc = fmaf(hv.z, ws[(k4 * 4 + 2) * 64 + lane], acc);
    acc = fmaf(hv.w, ws[(k4 * 4 + 3) * 64 + lane], acc);
  }
  y[(size_t)i * 64 + lane] = acc;
}

// ---------------------------------------------------------------------------

extern "C" void kernel_launch(void* const* d_in, const int* in_sizes, int n_in,
                              void* d_out, int out_size, void* d_ws, size_t ws_size,
                              hipStream_t stream) {
  const float* X  = (const float*)d_in[0];
  const int* ei   = (const int*)d_in[1];
  const float* gw1 = (const float*)d_in[3];
  const float* gb1 = (const float*)d_in[4];
  const float* lw1 = (const float*)d_in[5];
  const float* lb1 = (const float*)d_in[6];
  const float* gw2 = (const float*)d_in[7];
  const float* gb2 = (const float*)d_in[8];
  const float* lw2 = (const float*)d_in[9];
  const float* lb2 = (const float*)d_in[10];
  const float* gw3 = (const float*)d_in[11];
  const float* gb3 = (const float*)d_in[12];
  const float* lw3 = (const float*)d_in[13];
  const float* lb3 = (const float*)d_in[14];
  const float* fcw = (const float*)d_in[15];
  const float* fcb = (const float*)d_in[16];

  const int n = in_sizes[0] / 128;
  const int E = in_sizes[1] / 2;
  const int tot = E + n;

  char* ws = (char*)d_ws;
  size_t off = 0;
  auto alloc = [&](size_t bytes) -> void* {
    void* p = ws + off;
    off = (off + bytes + 255) & ~(size_t)255;
    return p;
  };
  const int gN = (n + 255) / 256;   // node blocks = buckets (<=512 required)
  int* deg     = (int*)alloc((size_t)n * 4);
  float* dis   = (float*)alloc((size_t)n * 4);
  int* rowptr  = (int*)alloc((size_t)(n + 1) * 4);
  int* fillctr = (int*)alloc((size_t)n * 4);
  int* partial = (int*)alloc((size_t)gN * 4);
  int* poff    = (int*)alloc((size_t)gN * 4);
  int* boff    = (int*)alloc((size_t)(gN + 1) * 4);
  int* bfill   = (int*)alloc((size_t)gN * 4);
  int* col     = (int*)alloc((size_t)tot * 4);
  unsigned int* ebuf = (unsigned int*)alloc((size_t)E * 4);
  u16* Xb      = (u16*)alloc((size_t)n * 128 * 2);
  u16* SXb     = (u16*)alloc((size_t)n * 128 * 2);
  u16* WT      = (u16*)alloc((size_t)6 * 16384 * 2);
  float* bias  = (float*)alloc(384 * 4);          // total ~66.8 MB

  float* outh = (float*)d_out;                 // [n,128] final h fp32
  float* outy = outh + (size_t)n * 128;        // [n,64]  final y fp32
  u16* hb = (u16*)outy;  // bf16 h ping-buffer in y-region (exact fit);
                         // overwritten by k_fc at the very end of every call.

  const int gE = (E + 255) / 256;
  const int gM = (n + 127) / 128;
  const int gW = (n + 3) / 4;
  const int g8 = (n * 128 / 8 + 255) / 256;

  // ---- graph preprocessing ----
  hipMemsetAsync(deg, 0, (size_t)n * 4, stream);
  k_count<<<gE, 256, 0, stream>>>(ei, deg, E);
  k_partial<<<gN, 256, 0, stream>>>(deg, partial, n);
  k_scanp<<<1, 512, 0, stream>>>(partial, poff, boff, bfill, gN, rowptr, n, tot, E);
  k_write<<<gN, 256, 0, stream>>>(deg, poff, rowptr, fillctr, col, dis, n);
  k_bin<<<gE, 256, 0, stream>>>(ei, bfill, ebuf, E);
  k_cfill<<<gN, 256, 0, stream>>>(ebuf, boff, fillctr, col);

  // ---- dtype prep ----
  k_cvt<<<g8, 256, 0, stream>>>(X, Xb, n * 128 / 8);
  k_prep<<<771, 128, 0, stream>>>(gw1, lw1, gw2, lw2, gw3, lw3,
                                  gb1, lb1, gb2, lb2, gb3, lb3, WT, bias);

  // ---- layer 1 ----
  k_spmv_bf<<<gW, 256, 0, stream>>>(rowptr, col, dis, Xb, SXb, n);
  k_mfma<<<gM, 256, 0, stream>>>(SXb, Xb, WT, WT + 16384, bias, hb, nullptr, n);
  // ---- layer 2 (hb in-place: each block writes only its own rows) ----
  k_spmv_bf<<<gW, 256, 0, stream>>>(rowptr, col, dis, hb, SXb, n);
  k_mfma<<<gM, 256, 0, stream>>>(SXb, hb, WT + 2 * 16384, WT + 3 * 16384,
                                 bias + 128, hb, nullptr, n);
  // ---- layer 3: fp32 h -> d_out ----
  k_spmv_bf<<<gW, 256, 0, stream>>>(rowptr, col, dis, hb, SXb, n);
  k_mfma<<<gM, 256, 0, stream>>>(SXb, hb, WT + 4 * 16384, WT + 5 * 16384,
                                 bias + 256, nullptr, outh, n);
  // ---- FC head (reads fp32 h, writes y over hb) ----
  k_fc<<<gW, 256, 0, stream>>>(outh, fcw, fcb, outy, n);
}

// Round 6
// 599.748 us; speedup vs baseline: 2.0486x; 2.0486x over previous
//
#include <hip/hip_runtime.h>
#include <cstdint>
#include <cstddef>

// ---------------------------------------------------------------------------
// GCN 3-layer + FC head. Round 6: counting-sort CSR build (LDS histograms,
// no global atomic contention), cfill computes rowptr/dis/self-loops.
// B = ceil(n/256) buckets (<=512), G = 256 edge chunks.
// ---------------------------------------------------------------------------

typedef __attribute__((ext_vector_type(4))) float f32x4;
typedef __attribute__((ext_vector_type(8))) short bf16x8;
typedef unsigned short u16;

#define G_CHUNKS 256

__device__ __forceinline__ float bf2f(unsigned int u) {
  union { unsigned int i; float f; } v;
  v.i = u << 16;
  return v.f;
}
__device__ __forceinline__ u16 f2bf(float f) {
  union { float f; unsigned int i; } v;
  v.f = f;
  unsigned int i = v.i;
  return (u16)((i + 0x7FFFu + ((i >> 16) & 1u)) >> 16);  // RNE
}

// ---------------- CSR build: counting sort by dst bucket ----------------

// pass 1: per-chunk histogram over B buckets -> ghist[b*G + g]
__global__ __launch_bounds__(256) void k_hist(const int* __restrict__ ei,
                                              int* __restrict__ ghist,
                                              int E, int B, int chunk) {
  __shared__ int h[512];
  for (int t = threadIdx.x; t < B; t += 256) h[t] = 0;
  __syncthreads();
  const int g = blockIdx.x;
  const int beg = g * chunk;
  const int end = min(beg + chunk, E);
  for (int e = beg + threadIdx.x; e < end; e += 256)
    atomicAdd(&h[ei[E + e] >> 8], 1);
  __syncthreads();
  for (int t = threadIdx.x; t < B; t += 256) ghist[(size_t)t * G_CHUNKS + g] = h[t];
}

// pass 2a: per-bucket exclusive scan over its G chunk-counts (in place) + total
__global__ __launch_bounds__(256) void k_hscan(int* __restrict__ ghist,
                                               int* __restrict__ btot) {
  __shared__ int sm[256];
  int* p = ghist + (size_t)blockIdx.x * G_CHUNKS;
  const int t = threadIdx.x;
  int v = p[t];
  sm[t] = v;
  __syncthreads();
  for (int off = 1; off < 256; off <<= 1) {
    int u = (t >= off) ? sm[t - off] : 0;
    __syncthreads();
    sm[t] += u;
    __syncthreads();
  }
  p[t] = sm[t] - v;                     // exclusive
  if (t == 255) btot[blockIdx.x] = sm[255];
}

// pass 2b: one block scans bucket totals -> boff; boff[B]=E; rowptr[n]=tot
__global__ __launch_bounds__(512) void k_bscan(const int* __restrict__ btot,
                                               int* __restrict__ boff, int B,
                                               int* __restrict__ rowptr, int n,
                                               int E, int tot) {
  __shared__ int sm[512];
  const int t = threadIdx.x;
  int v = (t < B) ? btot[t] : 0;
  sm[t] = v;
  __syncthreads();
  for (int off = 1; off < 512; off <<= 1) {
    int u = (t >= off) ? sm[t - off] : 0;
    __syncthreads();
    sm[t] += u;
    __syncthreads();
  }
  if (t < B) boff[t] = sm[t] - v;       // exclusive
  if (t == 0) {
    boff[B] = E;
    rowptr[n] = tot;
  }
}

// pass 3: scatter edges to bucket-major ebuf, packed (src<<8 | dst&255).
// LDS running offsets: contention stays on-chip; global writes sequential.
__global__ __launch_bounds__(256) void k_scatter(const int* __restrict__ ei,
                                                 const int* __restrict__ ghist,
                                                 const int* __restrict__ boff,
                                                 unsigned int* __restrict__ ebuf,
                                                 int E, int B, int chunk) {
  __shared__ int off[512];
  const int g = blockIdx.x;
  for (int t = threadIdx.x; t < B; t += 256)
    off[t] = boff[t] + ghist[(size_t)t * G_CHUNKS + g];
  __syncthreads();
  const int beg = g * chunk;
  const int end = min(beg + chunk, E);
  for (int e = beg + threadIdx.x; e < end; e += 256) {
    int s = ei[e];
    int d = ei[E + e];
    int pos = atomicAdd(&off[d >> 8], 1);
    ebuf[pos] = ((unsigned int)s << 8) | (unsigned int)(d & 255);
  }
}

// pass 4: one block per bucket. Count per-node, LDS scan -> rowptr/dis/
// self-loop slot, then fine-scatter col inside the bucket's L2-hot window.
__global__ __launch_bounds__(256) void k_cfill(const unsigned int* __restrict__ ebuf,
                                               const int* __restrict__ boff,
                                               int* __restrict__ rowptr,
                                               int* __restrict__ col,
                                               float* __restrict__ dis, int n) {
  __shared__ int cnt[256];
  __shared__ int fl[256];
  const int b = blockIdx.x;
  const int t = threadIdx.x;
  const int beg = boff[b];
  const int end = boff[b + 1];
  const int node0 = b << 8;
  const int nn = min(256, n - node0);
  cnt[t] = 0;
  __syncthreads();
  for (int e = beg + t; e < end; e += 256)
    atomicAdd(&cnt[ebuf[e] & 255u], 1);
  __syncthreads();
  int v = cnt[t];
  // inclusive scan of cnt
  __shared__ int sm[256];
  sm[t] = v;
  __syncthreads();
  for (int off = 1; off < 256; off <<= 1) {
    int u = (t >= off) ? sm[t - off] : 0;
    __syncthreads();
    sm[t] += u;
    __syncthreads();
  }
  if (t < nn) {
    int excl = sm[t] - v;
    int rbase = beg + node0 + t + excl;   // earlier buckets' edges + self-loops
    int i = node0 + t;
    rowptr[i] = rbase;
    col[rbase] = i;                        // self-loop first
    fl[t] = rbase + 1;
    dis[i] = rsqrtf((float)(v + 1));
  }
  __syncthreads();
  for (int e = beg + t; e < end; e += 256) {
    unsigned int pk = ebuf[e];
    int pos = atomicAdd(&fl[pk & 255u], 1);
    col[pos] = (int)(pk >> 8);
  }
}

// ---------------- dtype prep ----------------

__global__ __launch_bounds__(256) void k_cvt(const float* __restrict__ src,
                                             u16* __restrict__ dst, int total8) {
  int i = blockIdx.x * 256 + threadIdx.x;
  if (i >= total8) return;
  size_t b = (size_t)i * 8;
  float4 a0 = *(const float4*)(src + b);
  float4 a1 = *(const float4*)(src + b + 4);
  u16 o[8] = {f2bf(a0.x), f2bf(a0.y), f2bf(a0.z), f2bf(a0.w),
              f2bf(a1.x), f2bf(a1.y), f2bf(a1.z), f2bf(a1.w)};
  *(ulonglong2*)(dst + b) = *(ulonglong2*)o;
}

// blocks 0..767: WT[z][nr][k] = bf16(W_z[k][nr]); blocks 768..770: bias sums
__global__ __launch_bounds__(128) void k_prep(const float* __restrict__ w0,
                                              const float* __restrict__ w1,
                                              const float* __restrict__ w2,
                                              const float* __restrict__ w3,
                                              const float* __restrict__ w4,
                                              const float* __restrict__ w5,
                                              const float* __restrict__ g1,
                                              const float* __restrict__ l1,
                                              const float* __restrict__ g2,
                                              const float* __restrict__ l2,
                                              const float* __restrict__ g3,
                                              const float* __restrict__ l3,
                                              u16* __restrict__ wt,
                                              float* __restrict__ bias) {
  int bx = blockIdx.x;
  if (bx < 768) {
    int z = bx >> 7, nr = bx & 127, k = threadIdx.x;
    const float* Ws[6] = {w0, w1, w2, w3, w4, w5};
    wt[(size_t)z * 16384 + nr * 128 + k] = f2bf(Ws[z][k * 128 + nr]);
  } else {
    int t = (bx - 768) * 128 + threadIdx.x;
    if (t < 384) {
      const float* gs[3] = {g1, g2, g3};
      const float* ls[3] = {l1, l2, l3};
      bias[t] = gs[t >> 7][t & 127] + ls[t >> 7][t & 127];
    }
  }
}

// ---------------------------------------------------------------------------
// SXb[i] = bf16( dis[i] * sum_j dis[col[j]] * Xb[col[j], :] )
// one wave/node, uint (2xbf16)/lane, fp32 accum, 4-edge unroll for MLP.
// ---------------------------------------------------------------------------
__global__ __launch_bounds__(256) void k_spmv_bf(const int* __restrict__ rowptr,
                                                 const int* __restrict__ col,
                                                 const float* __restrict__ dis,
                                                 const u16* __restrict__ Xb,
                                                 u16* __restrict__ SXb, int n) {
  const int wave = threadIdx.x >> 6;
  const int lane = threadIdx.x & 63;
  const int i = blockIdx.x * 4 + wave;
  if (i >= n) return;
  int j = rowptr[i];
  const int end = rowptr[i + 1];
  float ax = 0.f, ay = 0.f;
  for (; j + 3 < end; j += 4) {
    int c0 = col[j], c1 = col[j + 1], c2 = col[j + 2], c3 = col[j + 3];
    float w0 = dis[c0], w1 = dis[c1], w2 = dis[c2], w3 = dis[c3];
    unsigned int q0 = *(const unsigned int*)(Xb + (size_t)c0 * 128 + lane * 2);
    unsigned int q1 = *(const unsigned int*)(Xb + (size_t)c1 * 128 + lane * 2);
    unsigned int q2 = *(const unsigned int*)(Xb + (size_t)c2 * 128 + lane * 2);
    unsigned int q3 = *(const unsigned int*)(Xb + (size_t)c3 * 128 + lane * 2);
    ax = fmaf(bf2f(q0 & 0xffffu), w0, ax);
    ay = fmaf(bf2f(q0 >> 16), w0, ay);
    ax = fmaf(bf2f(q1 & 0xffffu), w1, ax);
    ay = fmaf(bf2f(q1 >> 16), w1, ay);
    ax = fmaf(bf2f(q2 & 0xffffu), w2, ax);
    ay = fmaf(bf2f(q2 >> 16), w2, ay);
    ax = fmaf(bf2f(q3 & 0xffffu), w3, ax);
    ay = fmaf(bf2f(q3 >> 16), w3, ay);
  }
  for (; j < end; ++j) {
    int c0 = col[j];
    float w0 = dis[c0];
    unsigned int q0 = *(const unsigned int*)(Xb + (size_t)c0 * 128 + lane * 2);
    ax = fmaf(bf2f(q0 & 0xffffu), w0, ax);
    ay = fmaf(bf2f(q0 >> 16), w0, ay);
  }
  float di = dis[i];
  ax *= di;
  ay *= di;
  unsigned int o = (unsigned int)f2bf(ax) | ((unsigned int)f2bf(ay) << 16);
  *(unsigned int*)(SXb + (size_t)i * 128 + lane * 2) = o;
}

// ---------------------------------------------------------------------------
// MFMA fused layer:  out = lrelu( A0@W0 + A1@W1 + bias )
// A0,A1 bf16 row-major [M,128]; W0T,W1T bf16 [n][k]. No LDS.
// 4 waves/block, wave owns 32 rows; acc 2x8 f32x4.
// gfx950 16x16x32 mapping: A/B lane l -> row/col l&15, k (l>>4)*8+e;
//                          D lane l -> col l&15, row (l>>4)*4+e.
// ---------------------------------------------------------------------------
__global__ __launch_bounds__(256) void k_mfma(const u16* __restrict__ A0,
                                              const u16* __restrict__ A1,
                                              const u16* __restrict__ W0T,
                                              const u16* __restrict__ W1T,
                                              const float* __restrict__ bias,
                                              u16* __restrict__ outb,
                                              float* __restrict__ outf, int M) {
  const int lane = threadIdx.x & 63;
  const int wv = threadIdx.x >> 6;
  const int row0 = blockIdx.x * 128 + wv * 32;
  const int r = lane & 15;
  const int kg = lane >> 4;

  f32x4 acc[2][8];
#pragma unroll
  for (int a = 0; a < 2; ++a)
#pragma unroll
    for (int j = 0; j < 8; ++j) acc[a][j] = (f32x4){0.f, 0.f, 0.f, 0.f};

  const int ra0 = min(row0 + r, M - 1);
  const int ra1 = min(row0 + 16 + r, M - 1);

#pragma unroll
  for (int p = 0; p < 2; ++p) {
    const u16* A = p ? A1 : A0;
    const u16* WT = p ? W1T : W0T;
#pragma unroll
    for (int kk = 0; kk < 4; ++kk) {
      const int k0 = kk * 32 + kg * 8;
      bf16x8 a0 = *(const bf16x8*)(A + (size_t)ra0 * 128 + k0);
      bf16x8 a1 = *(const bf16x8*)(A + (size_t)ra1 * 128 + k0);
#pragma unroll
      for (int j = 0; j < 8; ++j) {
        bf16x8 b = *(const bf16x8*)(WT + (size_t)(j * 16 + r) * 128 + k0);
        acc[0][j] = __builtin_amdgcn_mfma_f32_16x16x32_bf16(a0, b, acc[0][j], 0, 0, 0);
        acc[1][j] = __builtin_amdgcn_mfma_f32_16x16x32_bf16(a1, b, acc[1][j], 0, 0, 0);
      }
    }
  }

#pragma unroll
  for (int rf = 0; rf < 2; ++rf)
#pragma unroll
    for (int e = 0; e < 4; ++e) {
      const int row = row0 + rf * 16 + kg * 4 + e;
      if (row >= M) continue;
#pragma unroll
      for (int j = 0; j < 8; ++j) {
        const int c = j * 16 + r;
        float v = acc[rf][j][e] + bias[c];
        v = (v > 0.f) ? v : 0.01f * v;
        if (outf) outf[(size_t)row * 128 + c] = v;
        else outb[(size_t)row * 128 + c] = f2bf(v);
      }
    }
}

// ---------------------------------------------------------------------------
// FC head: y = h @ fcw + fcb   ([N,128]x[128,64] fp32); one wave per row.
// ---------------------------------------------------------------------------
__global__ __launch_bounds__(256) void k_fc(const float* __restrict__ h,
                                            const float* __restrict__ fcw,
                                            const float* __restrict__ fcb,
                                            float* __restrict__ y, int n) {
  __shared__ float ws[128 * 64];
  for (int t = threadIdx.x; t < 128 * 64; t += 256) ws[t] = fcw[t];
  __syncthreads();
  const int wave = threadIdx.x >> 6;
  const int lane = threadIdx.x & 63;
  const int i = blockIdx.x * 4 + wave;
  if (i >= n) return;
  const float* hr = h + (size_t)i * 128;
  float acc = fcb[lane];
#pragma unroll 8
  for (int k4 = 0; k4 < 32; ++k4) {
    float4 hv = *(const float4*)(hr + k4 * 4);
    acc = fmaf(hv.x, ws[(k4 * 4 + 0) * 64 + lane], acc);
    acc = fmaf(hv.y, ws[(k4 * 4 + 1) * 64 + lane], acc);
    acc = fmaf(hv.z, ws[(k4 * 4 + 2) * 64 + lane], acc);
    acc = fmaf(hv.w, ws[(k4 * 4 + 3) * 64 + lane], acc);
  }
  y[(size_t)i * 64 + lane] = acc;
}

// ---------------------------------------------------------------------------

extern "C" void kernel_launch(void* const* d_in, const int* in_sizes, int n_in,
                              void* d_out, int out_size, void* d_ws, size_t ws_size,
                              hipStream_t stream) {
  const float* X  = (const float*)d_in[0];
  const int* ei   = (const int*)d_in[1];
  const float* gw1 = (const float*)d_in[3];
  const float* gb1 = (const float*)d_in[4];
  const float* lw1 = (const float*)d_in[5];
  const float* lb1 = (const float*)d_in[6];
  const float* gw2 = (const float*)d_in[7];
  const float* gb2 = (const float*)d_in[8];
  const float* lw2 = (const float*)d_in[9];
  const float* lb2 = (const float*)d_in[10];
  const float* gw3 = (const float*)d_in[11];
  const float* gb3 = (const float*)d_in[12];
  const float* lw3 = (const float*)d_in[13];
  const float* lb3 = (const float*)d_in[14];
  const float* fcw = (const float*)d_in[15];
  const float* fcb = (const float*)d_in[16];

  const int n = in_sizes[0] / 128;
  const int E = in_sizes[1] / 2;
  const int tot = E + n;
  const int B = (n + 255) >> 8;        // buckets (<=512)
  const int chunk = (E + G_CHUNKS - 1) / G_CHUNKS;

  char* ws = (char*)d_ws;
  size_t off = 0;
  auto alloc = [&](size_t bytes) -> void* {
    void* p = ws + off;
    off = (off + bytes + 255) & ~(size_t)255;
    return p;
  };
  int* ghist   = (int*)alloc((size_t)B * G_CHUNKS * 4);
  int* btot    = (int*)alloc(512 * 4);
  int* boff    = (int*)alloc((size_t)(B + 1) * 4);
  int* rowptr  = (int*)alloc((size_t)(n + 1) * 4);
  float* dis   = (float*)alloc((size_t)n * 4);
  int* col     = (int*)alloc((size_t)tot * 4);
  unsigned int* ebuf = (unsigned int*)alloc((size_t)E * 4);
  u16* Xb      = (u16*)alloc((size_t)n * 128 * 2);
  u16* SXb     = (u16*)alloc((size_t)n * 128 * 2);
  u16* WT      = (u16*)alloc((size_t)6 * 16384 * 2);
  float* bias  = (float*)alloc(384 * 4);          // total ~66 MB

  float* outh = (float*)d_out;                 // [n,128] final h fp32
  float* outy = outh + (size_t)n * 128;        // [n,64]  final y fp32
  u16* hb = (u16*)outy;  // bf16 h ping-buffer in y-region (exact fit);
                         // overwritten by k_fc at the very end of every call.

  const int gM = (n + 127) / 128;
  const int gW = (n + 3) / 4;
  const int g8 = (n * 128 / 8 + 255) / 256;

  // ---- CSR build (counting sort) ----
  k_hist<<<G_CHUNKS, 256, 0, stream>>>(ei, ghist, E, B, chunk);
  k_hscan<<<B, 256, 0, stream>>>(ghist, btot);
  k_bscan<<<1, 512, 0, stream>>>(btot, boff, B, rowptr, n, E, tot);
  k_scatter<<<G_CHUNKS, 256, 0, stream>>>(ei, ghist, boff, ebuf, E, B, chunk);
  k_cfill<<<B, 256, 0, stream>>>(ebuf, boff, rowptr, col, dis, n);

  // ---- dtype prep ----
  k_cvt<<<g8, 256, 0, stream>>>(X, Xb, n * 128 / 8);
  k_prep<<<771, 128, 0, stream>>>(gw1, lw1, gw2, lw2, gw3, lw3,
                                  gb1, lb1, gb2, lb2, gb3, lb3, WT, bias);

  // ---- layer 1 ----
  k_spmv_bf<<<gW, 256, 0, stream>>>(rowptr, col, dis, Xb, SXb, n);
  k_mfma<<<gM, 256, 0, stream>>>(SXb, Xb, WT, WT + 16384, bias, hb, nullptr, n);
  // ---- layer 2 (hb in-place: each block writes only its own rows) ----
  k_spmv_bf<<<gW, 256, 0, stream>>>(rowptr, col, dis, hb, SXb, n);
  k_mfma<<<gM, 256, 0, stream>>>(SXb, hb, WT + 2 * 16384, WT + 3 * 16384,
                                 bias + 128, hb, nullptr, n);
  // ---- layer 3: fp32 h -> d_out ----
  k_spmv_bf<<<gW, 256, 0, stream>>>(rowptr, col, dis, hb, SXb, n);
  k_mfma<<<gM, 256, 0, stream>>>(SXb, hb, WT + 4 * 16384, WT + 5 * 16384,
                                 bias + 256, nullptr, outh, n);
  // ---- FC head (reads fp32 h, writes y over hb) ----
  k_fc<<<gW, 256, 0, stream>>>(outh, fcw, fcb, outy, n);
}

// Round 7
// 522.497 us; speedup vs baseline: 2.3515x; 1.1479x over previous
//
#include <hip/hip_runtime.h>
#include <cstdint>
#include <cstddef>

// ---------------------------------------------------------------------------
// GCN 3-layer + FC head. Round 7: FC head as MFMA (kills 131us LDS-staged
// k_fc), layer-3 mfma emits bf16 h copy, spmv int4 col loads.
// ---------------------------------------------------------------------------

typedef __attribute__((ext_vector_type(4))) float f32x4;
typedef __attribute__((ext_vector_type(8))) short bf16x8;
typedef unsigned short u16;

#define G_CHUNKS 256

__device__ __forceinline__ float bf2f(unsigned int u) {
  union { unsigned int i; float f; } v;
  v.i = u << 16;
  return v.f;
}
__device__ __forceinline__ u16 f2bf(float f) {
  union { float f; unsigned int i; } v;
  v.f = f;
  unsigned int i = v.i;
  return (u16)((i + 0x7FFFu + ((i >> 16) & 1u)) >> 16);  // RNE
}

// ---------------- CSR build: counting sort by dst bucket ----------------

__global__ __launch_bounds__(256) void k_hist(const int* __restrict__ ei,
                                              int* __restrict__ ghist,
                                              int E, int B, int chunk) {
  __shared__ int h[512];
  for (int t = threadIdx.x; t < B; t += 256) h[t] = 0;
  __syncthreads();
  const int g = blockIdx.x;
  const int beg = g * chunk;
  const int end = min(beg + chunk, E);
  for (int e = beg + threadIdx.x; e < end; e += 256)
    atomicAdd(&h[ei[E + e] >> 8], 1);
  __syncthreads();
  for (int t = threadIdx.x; t < B; t += 256) ghist[(size_t)t * G_CHUNKS + g] = h[t];
}

__global__ __launch_bounds__(256) void k_hscan(int* __restrict__ ghist,
                                               int* __restrict__ btot) {
  __shared__ int sm[256];
  int* p = ghist + (size_t)blockIdx.x * G_CHUNKS;
  const int t = threadIdx.x;
  int v = p[t];
  sm[t] = v;
  __syncthreads();
  for (int off = 1; off < 256; off <<= 1) {
    int u = (t >= off) ? sm[t - off] : 0;
    __syncthreads();
    sm[t] += u;
    __syncthreads();
  }
  p[t] = sm[t] - v;                     // exclusive
  if (t == 255) btot[blockIdx.x] = sm[255];
}

__global__ __launch_bounds__(512) void k_bscan(const int* __restrict__ btot,
                                               int* __restrict__ boff, int B,
                                               int* __restrict__ rowptr, int n,
                                               int E, int tot) {
  __shared__ int sm[512];
  const int t = threadIdx.x;
  int v = (t < B) ? btot[t] : 0;
  sm[t] = v;
  __syncthreads();
  for (int off = 1; off < 512; off <<= 1) {
    int u = (t >= off) ? sm[t - off] : 0;
    __syncthreads();
    sm[t] += u;
    __syncthreads();
  }
  if (t < B) boff[t] = sm[t] - v;       // exclusive
  if (t == 0) {
    boff[B] = E;
    rowptr[n] = tot;
  }
}

__global__ __launch_bounds__(256) void k_scatter(const int* __restrict__ ei,
                                                 const int* __restrict__ ghist,
                                                 const int* __restrict__ boff,
                                                 unsigned int* __restrict__ ebuf,
                                                 int E, int B, int chunk) {
  __shared__ int off[512];
  const int g = blockIdx.x;
  for (int t = threadIdx.x; t < B; t += 256)
    off[t] = boff[t] + ghist[(size_t)t * G_CHUNKS + g];
  __syncthreads();
  const int beg = g * chunk;
  const int end = min(beg + chunk, E);
  for (int e = beg + threadIdx.x; e < end; e += 256) {
    int s = ei[e];
    int d = ei[E + e];
    int pos = atomicAdd(&off[d >> 8], 1);
    ebuf[pos] = ((unsigned int)s << 8) | (unsigned int)(d & 255);
  }
}

__global__ __launch_bounds__(256) void k_cfill(const unsigned int* __restrict__ ebuf,
                                               const int* __restrict__ boff,
                                               int* __restrict__ rowptr,
                                               int* __restrict__ col,
                                               float* __restrict__ dis, int n) {
  __shared__ int cnt[256];
  __shared__ int fl[256];
  const int b = blockIdx.x;
  const int t = threadIdx.x;
  const int beg = boff[b];
  const int end = boff[b + 1];
  const int node0 = b << 8;
  const int nn = min(256, n - node0);
  cnt[t] = 0;
  __syncthreads();
  for (int e = beg + t; e < end; e += 256)
    atomicAdd(&cnt[ebuf[e] & 255u], 1);
  __syncthreads();
  int v = cnt[t];
  __shared__ int sm[256];
  sm[t] = v;
  __syncthreads();
  for (int off = 1; off < 256; off <<= 1) {
    int u = (t >= off) ? sm[t - off] : 0;
    __syncthreads();
    sm[t] += u;
    __syncthreads();
  }
  if (t < nn) {
    int excl = sm[t] - v;
    int rbase = beg + node0 + t + excl;   // earlier buckets' edges + self-loops
    int i = node0 + t;
    rowptr[i] = rbase;
    col[rbase] = i;                        // self-loop first
    fl[t] = rbase + 1;
    dis[i] = rsqrtf((float)(v + 1));
  }
  __syncthreads();
  for (int e = beg + t; e < end; e += 256) {
    unsigned int pk = ebuf[e];
    int pos = atomicAdd(&fl[pk & 255u], 1);
    col[pos] = (int)(pk >> 8);
  }
}

// ---------------- dtype prep ----------------

__global__ __launch_bounds__(256) void k_cvt(const float* __restrict__ src,
                                             u16* __restrict__ dst, int total8) {
  int i = blockIdx.x * 256 + threadIdx.x;
  if (i >= total8) return;
  size_t b = (size_t)i * 8;
  float4 a0 = *(const float4*)(src + b);
  float4 a1 = *(const float4*)(src + b + 4);
  u16 o[8] = {f2bf(a0.x), f2bf(a0.y), f2bf(a0.z), f2bf(a0.w),
              f2bf(a1.x), f2bf(a1.y), f2bf(a1.z), f2bf(a1.w)};
  *(ulonglong2*)(dst + b) = *(ulonglong2*)o;
}

// blocks 0..767: WT[z][nr][k] = bf16(W_z[k][nr])
// blocks 768..770: bias sums; blocks 771..834: fcT[nr][k] = bf16(fcw[k][nr])
__global__ __launch_bounds__(128) void k_prep(const float* __restrict__ w0,
                                              const float* __restrict__ w1,
                                              const float* __restrict__ w2,
                                              const float* __restrict__ w3,
                                              const float* __restrict__ w4,
                                              const float* __restrict__ w5,
                                              const float* __restrict__ g1,
                                              const float* __restrict__ l1,
                                              const float* __restrict__ g2,
                                              const float* __restrict__ l2,
                                              const float* __restrict__ g3,
                                              const float* __restrict__ l3,
                                              const float* __restrict__ fcw,
                                              u16* __restrict__ wt,
                                              float* __restrict__ bias,
                                              u16* __restrict__ fcT) {
  int bx = blockIdx.x;
  if (bx < 768) {
    int z = bx >> 7, nr = bx & 127, k = threadIdx.x;
    const float* Ws[6] = {w0, w1, w2, w3, w4, w5};
    wt[(size_t)z * 16384 + nr * 128 + k] = f2bf(Ws[z][k * 128 + nr]);
  } else if (bx < 771) {
    int t = (bx - 768) * 128 + threadIdx.x;
    if (t < 384) {
      const float* gs[3] = {g1, g2, g3};
      const float* ls[3] = {l1, l2, l3};
      bias[t] = gs[t >> 7][t & 127] + ls[t >> 7][t & 127];
    }
  } else {
    int nr = bx - 771;                 // 0..63
    int k = threadIdx.x;
    fcT[nr * 128 + k] = f2bf(fcw[k * 64 + nr]);
  }
}

// ---------------------------------------------------------------------------
// SXb[i] = bf16( dis[i] * sum_j dis[col[j]] * Xb[col[j], :] )
// one wave/node; col loaded as aligned int4 (CSR-contiguous).
// ---------------------------------------------------------------------------
__global__ __launch_bounds__(256) void k_spmv_bf(const int* __restrict__ rowptr,
                                                 const int* __restrict__ col,
                                                 const float* __restrict__ dis,
                                                 const u16* __restrict__ Xb,
                                                 u16* __restrict__ SXb, int n) {
  const int wave = threadIdx.x >> 6;
  const int lane = threadIdx.x & 63;
  const int i = blockIdx.x * 4 + wave;
  if (i >= n) return;
  int j = rowptr[i];
  const int end = rowptr[i + 1];
  float ax = 0.f, ay = 0.f;

  // peel to 16B alignment of col+j
  for (; (j & 3) && j < end; ++j) {
    int c0 = col[j];
    float w0 = dis[c0];
    unsigned int q0 = *(const unsigned int*)(Xb + (size_t)c0 * 128 + lane * 2);
    ax = fmaf(bf2f(q0 & 0xffffu), w0, ax);
    ay = fmaf(bf2f(q0 >> 16), w0, ay);
  }
  for (; j + 3 < end; j += 4) {
    int4 c4 = *(const int4*)(col + j);
    float w0 = dis[c4.x], w1 = dis[c4.y], w2 = dis[c4.z], w3 = dis[c4.w];
    unsigned int q0 = *(const unsigned int*)(Xb + (size_t)c4.x * 128 + lane * 2);
    unsigned int q1 = *(const unsigned int*)(Xb + (size_t)c4.y * 128 + lane * 2);
    unsigned int q2 = *(const unsigned int*)(Xb + (size_t)c4.z * 128 + lane * 2);
    unsigned int q3 = *(const unsigned int*)(Xb + (size_t)c4.w * 128 + lane * 2);
    ax = fmaf(bf2f(q0 & 0xffffu), w0, ax);
    ay = fmaf(bf2f(q0 >> 16), w0, ay);
    ax = fmaf(bf2f(q1 & 0xffffu), w1, ax);
    ay = fmaf(bf2f(q1 >> 16), w1, ay);
    ax = fmaf(bf2f(q2 & 0xffffu), w2, ax);
    ay = fmaf(bf2f(q2 >> 16), w2, ay);
    ax = fmaf(bf2f(q3 & 0xffffu), w3, ax);
    ay = fmaf(bf2f(q3 >> 16), w3, ay);
  }
  for (; j < end; ++j) {
    int c0 = col[j];
    float w0 = dis[c0];
    unsigned int q0 = *(const unsigned int*)(Xb + (size_t)c0 * 128 + lane * 2);
    ax = fmaf(bf2f(q0 & 0xffffu), w0, ax);
    ay = fmaf(bf2f(q0 >> 16), w0, ay);
  }
  float di = dis[i];
  ax *= di;
  ay *= di;
  unsigned int o = (unsigned int)f2bf(ax) | ((unsigned int)f2bf(ay) << 16);
  *(unsigned int*)(SXb + (size_t)i * 128 + lane * 2) = o;
}

// ---------------------------------------------------------------------------
// MFMA fused layer:  out = lrelu( A0@W0 + A1@W1 + bias )
// A0,A1 bf16 row-major [M,128]; W0T,W1T bf16 [n][k]. No LDS.
// Writes outb (bf16) and/or outf (fp32) -- both for layer 3.
// gfx950 16x16x32 mapping: A/B lane l -> row/col l&15, k (l>>4)*8+e;
//                          D lane l -> col l&15, row (l>>4)*4+e.
// ---------------------------------------------------------------------------
__global__ __launch_bounds__(256) void k_mfma(const u16* __restrict__ A0,
                                              const u16* __restrict__ A1,
                                              const u16* __restrict__ W0T,
                                              const u16* __restrict__ W1T,
                                              const float* __restrict__ bias,
                                              u16* __restrict__ outb,
                                              float* __restrict__ outf, int M) {
  const int lane = threadIdx.x & 63;
  const int wv = threadIdx.x >> 6;
  const int row0 = blockIdx.x * 128 + wv * 32;
  const int r = lane & 15;
  const int kg = lane >> 4;

  f32x4 acc[2][8];
#pragma unroll
  for (int a = 0; a < 2; ++a)
#pragma unroll
    for (int j = 0; j < 8; ++j) acc[a][j] = (f32x4){0.f, 0.f, 0.f, 0.f};

  const int ra0 = min(row0 + r, M - 1);
  const int ra1 = min(row0 + 16 + r, M - 1);

#pragma unroll
  for (int p = 0; p < 2; ++p) {
    const u16* A = p ? A1 : A0;
    const u16* WT = p ? W1T : W0T;
#pragma unroll
    for (int kk = 0; kk < 4; ++kk) {
      const int k0 = kk * 32 + kg * 8;
      bf16x8 a0 = *(const bf16x8*)(A + (size_t)ra0 * 128 + k0);
      bf16x8 a1 = *(const bf16x8*)(A + (size_t)ra1 * 128 + k0);
#pragma unroll
      for (int j = 0; j < 8; ++j) {
        bf16x8 b = *(const bf16x8*)(WT + (size_t)(j * 16 + r) * 128 + k0);
        acc[0][j] = __builtin_amdgcn_mfma_f32_16x16x32_bf16(a0, b, acc[0][j], 0, 0, 0);
        acc[1][j] = __builtin_amdgcn_mfma_f32_16x16x32_bf16(a1, b, acc[1][j], 0, 0, 0);
      }
    }
  }

#pragma unroll
  for (int rf = 0; rf < 2; ++rf)
#pragma unroll
    for (int e = 0; e < 4; ++e) {
      const int row = row0 + rf * 16 + kg * 4 + e;
      if (row >= M) continue;
#pragma unroll
      for (int j = 0; j < 8; ++j) {
        const int c = j * 16 + r;
        float v = acc[rf][j][e] + bias[c];
        v = (v > 0.f) ? v : 0.01f * v;
        if (outf) outf[(size_t)row * 128 + c] = v;
        if (outb) outb[(size_t)row * 128 + c] = f2bf(v);
      }
    }
}

// ---------------------------------------------------------------------------
// FC head via MFMA: y = h @ fcw + fcb. hb3 bf16 [M,128], fcT bf16 [64][128].
// ---------------------------------------------------------------------------
__global__ __launch_bounds__(256) void k_fc_mfma(const u16* __restrict__ hb3,
                                                 const u16* __restrict__ fcT,
                                                 const float* __restrict__ fcb,
                                                 float* __restrict__ y, int M) {
  const int lane = threadIdx.x & 63;
  const int wv = threadIdx.x >> 6;
  const int row0 = blockIdx.x * 128 + wv * 32;
  const int r = lane & 15;
  const int kg = lane >> 4;

  f32x4 acc[2][4];
#pragma unroll
  for (int a = 0; a < 2; ++a)
#pragma unroll
    for (int j = 0; j < 4; ++j) acc[a][j] = (f32x4){0.f, 0.f, 0.f, 0.f};

  const int ra0 = min(row0 + r, M - 1);
  const int ra1 = min(row0 + 16 + r, M - 1);

#pragma unroll
  for (int kk = 0; kk < 4; ++kk) {
    const int k0 = kk * 32 + kg * 8;
    bf16x8 a0 = *(const bf16x8*)(hb3 + (size_t)ra0 * 128 + k0);
    bf16x8 a1 = *(const bf16x8*)(hb3 + (size_t)ra1 * 128 + k0);
#pragma unroll
    for (int j = 0; j < 4; ++j) {
      bf16x8 b = *(const bf16x8*)(fcT + (size_t)(j * 16 + r) * 128 + k0);
      acc[0][j] = __builtin_amdgcn_mfma_f32_16x16x32_bf16(a0, b, acc[0][j], 0, 0, 0);
      acc[1][j] = __builtin_amdgcn_mfma_f32_16x16x32_bf16(a1, b, acc[1][j], 0, 0, 0);
    }
  }

#pragma unroll
  for (int rf = 0; rf < 2; ++rf)
#pragma unroll
    for (int e = 0; e < 4; ++e) {
      const int row = row0 + rf * 16 + kg * 4 + e;
      if (row >= M) continue;
#pragma unroll
      for (int j = 0; j < 4; ++j) {
        const int c = j * 16 + r;
        y[(size_t)row * 64 + c] = acc[rf][j][e] + fcb[c];
      }
    }
}

// ---------------------------------------------------------------------------

extern "C" void kernel_launch(void* const* d_in, const int* in_sizes, int n_in,
                              void* d_out, int out_size, void* d_ws, size_t ws_size,
                              hipStream_t stream) {
  const float* X  = (const float*)d_in[0];
  const int* ei   = (const int*)d_in[1];
  const float* gw1 = (const float*)d_in[3];
  const float* gb1 = (const float*)d_in[4];
  const float* lw1 = (const float*)d_in[5];
  const float* lb1 = (const float*)d_in[6];
  const float* gw2 = (const float*)d_in[7];
  const float* gb2 = (const float*)d_in[8];
  const float* lw2 = (const float*)d_in[9];
  const float* lb2 = (const float*)d_in[10];
  const float* gw3 = (const float*)d_in[11];
  const float* gb3 = (const float*)d_in[12];
  const float* lw3 = (const float*)d_in[13];
  const float* lb3 = (const float*)d_in[14];
  const float* fcw = (const float*)d_in[15];
  const float* fcb = (const float*)d_in[16];

  const int n = in_sizes[0] / 128;
  const int E = in_sizes[1] / 2;
  const int tot = E + n;
  const int B = (n + 255) >> 8;        // buckets (<=512)
  const int chunk = (E + G_CHUNKS - 1) / G_CHUNKS;

  char* ws = (char*)d_ws;
  size_t off = 0;
  auto alloc = [&](size_t bytes) -> void* {
    void* p = ws + off;
    off = (off + bytes + 255) & ~(size_t)255;
    return p;
  };
  int* ghist   = (int*)alloc((size_t)B * G_CHUNKS * 4);
  int* btot    = (int*)alloc(512 * 4);
  int* boff    = (int*)alloc((size_t)(B + 1) * 4);
  int* rowptr  = (int*)alloc((size_t)(n + 1) * 4);
  float* dis   = (float*)alloc((size_t)n * 4);
  int* col     = (int*)alloc((size_t)tot * 4);
  unsigned int* ebuf = (unsigned int*)alloc((size_t)E * 4);
  u16* Xb      = (u16*)alloc((size_t)n * 128 * 2);   // X bf16; later h3 bf16
  u16* SXb     = (u16*)alloc((size_t)n * 128 * 2);
  u16* WT      = (u16*)alloc((size_t)6 * 16384 * 2);
  u16* fcT     = (u16*)alloc((size_t)64 * 128 * 2);
  float* bias  = (float*)alloc(384 * 4);          // total ~66 MB

  float* outh = (float*)d_out;                 // [n,128] final h fp32
  float* outy = outh + (size_t)n * 128;        // [n,64]  final y fp32
  u16* hb = (u16*)outy;  // bf16 h ping (layers 1-2) in y-region (exact fit);
                         // overwritten by k_fc_mfma at the end of every call.

  const int gM = (n + 127) / 128;
  const int gW = (n + 3) / 4;
  const int g8 = (n * 128 / 8 + 255) / 256;

  // ---- CSR build (counting sort) ----
  k_hist<<<G_CHUNKS, 256, 0, stream>>>(ei, ghist, E, B, chunk);
  k_hscan<<<B, 256, 0, stream>>>(ghist, btot);
  k_bscan<<<1, 512, 0, stream>>>(btot, boff, B, rowptr, n, E, tot);
  k_scatter<<<G_CHUNKS, 256, 0, stream>>>(ei, ghist, boff, ebuf, E, B, chunk);
  k_cfill<<<B, 256, 0, stream>>>(ebuf, boff, rowptr, col, dis, n);

  // ---- dtype prep ----
  k_cvt<<<g8, 256, 0, stream>>>(X, Xb, n * 128 / 8);
  k_prep<<<835, 128, 0, stream>>>(gw1, lw1, gw2, lw2, gw3, lw3,
                                  gb1, lb1, gb2, lb2, gb3, lb3, fcw,
                                  WT, bias, fcT);

  // ---- layer 1 ----
  k_spmv_bf<<<gW, 256, 0, stream>>>(rowptr, col, dis, Xb, SXb, n);
  k_mfma<<<gM, 256, 0, stream>>>(SXb, Xb, WT, WT + 16384, bias, hb, nullptr, n);
  // ---- layer 2 (hb in-place: each block writes only its own rows) ----
  k_spmv_bf<<<gW, 256, 0, stream>>>(rowptr, col, dis, hb, SXb, n);
  k_mfma<<<gM, 256, 0, stream>>>(SXb, hb, WT + 2 * 16384, WT + 3 * 16384,
                                 bias + 128, hb, nullptr, n);
  // ---- layer 3: fp32 h -> d_out, bf16 h -> Xb (free since layer 1) ----
  k_spmv_bf<<<gW, 256, 0, stream>>>(rowptr, col, dis, hb, SXb, n);
  k_mfma<<<gM, 256, 0, stream>>>(SXb, hb, WT + 4 * 16384, WT + 5 * 16384,
                                 bias + 256, Xb, outh, n);
  // ---- FC head via MFMA (reads bf16 h3 in Xb, writes y) ----
  k_fc_mfma<<<gM, 256, 0, stream>>>(Xb, fcT, fcb, outy, n);
}